// Round 5
// baseline (63.067 us; speedup 1.0000x reference)
//
#include <hip/hip_runtime.h>
#include <stdint.h>

#define EE 1024
#define SS 512
#define NBATCH 16
#define PP 96
#define NROWS (NBATCH * SS)   // 8192
#define NJ (PP * 4)           // 384
#define EPS 1e-8f

typedef __attribute__((ext_vector_type(8))) short bf16x8;
typedef __attribute__((ext_vector_type(4))) float f32x4;

// round-to-nearest-even f32 -> bf16 bits
__device__ __forceinline__ ushort f2bf(float f) {
    uint32_t u = __float_as_uint(f);
    u += 0x7fffu + ((u >> 16) & 1u);
    return (ushort)(u >> 16);
}

__device__ __forceinline__ void gload16(const void* g, void* l) {
    __builtin_amdgcn_global_load_lds(
        (const __attribute__((address_space(1))) uint32_t*)g,
        (__attribute__((address_space(3))) uint32_t*)l, 16, 0, 0);
}

// ---- fused convert: emb (wave-per-row, 4xfloat4/lane) + proto; zeros cls ----
__global__ __launch_bounds__(256) void conv_kernel(const float* __restrict__ emb,
                                                   const float* __restrict__ proto,
                                                   ushort* __restrict__ ebf,
                                                   ushort* __restrict__ pbf,
                                                   float* __restrict__ rn2,
                                                   float* __restrict__ pn,
                                                   float* __restrict__ cls) {
    int b = blockIdx.x, t = threadIdx.x;
    if (b < NROWS / 4) {
        int r = b * 4 + (t >> 6);
        int l = t & 63;
        const float4* src = (const float4*)(emb + (size_t)r * EE);
        ushort4* dst = (ushort4*)(ebf + (size_t)r * EE);
        float s = 0.f;
#pragma unroll
        for (int i = 0; i < 4; i++) {
            float4 v = src[l + 64 * i];
            dst[l + 64 * i] = make_ushort4(f2bf(v.x), f2bf(v.y), f2bf(v.z), f2bf(v.w));
            s += v.x * v.x + v.y * v.y + v.z * v.z + v.w * v.w;
        }
#pragma unroll
        for (int off = 32; off; off >>= 1) s += __shfl_down(s, off);
        if (l == 0) rn2[r] = s;
    } else {
        int p = b - NROWS / 4;
        if (p == 0 && t < NBATCH * 2) cls[t] = 0.f;   // zero FC accumulators
        const float4* src = (const float4*)(proto + (size_t)p * 4096);
        ushort4* dst = (ushort4*)(pbf + (size_t)p * 4096);
        float s = 0.f;
#pragma unroll
        for (int i = 0; i < 4; i++) {
            float4 v = src[t + 256 * i];
            dst[t + 256 * i] = make_ushort4(f2bf(v.x), f2bf(v.y), f2bf(v.z), f2bf(v.w));
            s += v.x * v.x + v.y * v.y + v.z * v.z + v.w * v.w;
        }
#pragma unroll
        for (int off = 32; off; off >>= 1) s += __shfl_down(s, off);
        __shared__ float red[4];
        if ((t & 63) == 0) red[t >> 6] = s;
        __syncthreads();
        if (t == 0) pn[p] = sqrtf(red[0] + red[1] + red[2] + red[3]);
    }
}

// ---- bf16 MFMA GEMM (r2-proven): Rt[split][j][r], 128x128 tile, GBK=32, K-split 2 ----
#define GBM 128
#define GBN 128
#define GBK 32
#define NSPLIT 2

__global__ __launch_bounds__(256) void gemm_kernel(const ushort* __restrict__ A,
                                                   const ushort* __restrict__ B,
                                                   float* __restrict__ Rt) {
    __shared__ ushort As[GBM * GBK];
    __shared__ ushort Bs[GBN * GBK];
    const int per = (NROWS / GBM) * (NJ / GBN);  // 64*3 = 192
    int bid = blockIdx.x;
    int split = bid / per;
    int rem = bid - split * per;
    int bm = rem & 63;
    int bn = rem >> 6;
    const int klen = EE / NSPLIT;   // 512
    int kb = split * klen;
    int r0 = bm * GBM, j0 = bn * GBN;
    int tid = threadIdx.x;
    int lane = tid & 63;

    // staging: thread t -> LDS linear byte t*16 (= row t/4, chunk t&3 of 32-elem row)
    // pre-swizzled global chunk: c ^ (row & 3)   (involution)
    int srow = tid >> 2;
    int schunk = (tid & 3) ^ (srow & 3);
    const ushort* ga = A + (size_t)(r0 + srow) * EE + kb + schunk * 8;
    const ushort* gb = B + (size_t)(j0 + srow) * EE + kb + schunk * 8;
    ushort* lA = As + tid * 8;
    ushort* lB = Bs + tid * 8;

    int w = tid >> 6;
    int wm = (w >> 1) * 64, wn = (w & 1) * 64;
    int kc = lane >> 4;          // k-chunk 0..3
    int fr = lane & 15;
    int fchunk = kc ^ (fr & 3);  // swizzled read chunk

    f32x4 acc[4][4] = {};

    for (int k0 = 0; k0 < klen; k0 += GBK) {
        __syncthreads();
        gload16(ga + k0, lA);
        gload16(ga + 64 * EE + k0, lA + 2048);
        gload16(gb + k0, lB);
        gload16(gb + 64 * EE + k0, lB + 2048);
        __syncthreads();
        bf16x8 af[4], bfr[4];
#pragma unroll
        for (int m = 0; m < 4; m++)
            af[m] = *(const bf16x8*)(As + (wm + m * 16 + fr) * GBK + fchunk * 8);
#pragma unroll
        for (int n = 0; n < 4; n++)
            bfr[n] = *(const bf16x8*)(Bs + (wn + n * 16 + fr) * GBK + fchunk * 8);
#pragma unroll
        for (int m = 0; m < 4; m++)
#pragma unroll
            for (int n = 0; n < 4; n++)
                acc[m][n] = __builtin_amdgcn_mfma_f32_16x16x32_bf16(af[m], bfr[n], acc[m][n], 0, 0, 0);
    }

    float* Rbase = Rt + (size_t)split * NJ * NROWS;
    int rloc = r0 + wm + (lane >> 4) * 4;
    int jloc = j0 + wn + fr;
#pragma unroll
    for (int m = 0; m < 4; m++)
#pragma unroll
        for (int n = 0; n < 4; n++)
            *(f32x4*)(Rbase + (size_t)(jloc + n * 16) * NROWS + rloc + m * 16) = acc[m][n];
}

// ---- combine: min-pool of -cos; 2-plane partial sum; fused FC via atomics ----
__global__ __launch_bounds__(256) void combine_kernel(const float* __restrict__ Rt,
                                                      const float* __restrict__ rn2,
                                                      const float* __restrict__ pn,
                                                      const float* __restrict__ fcw,
                                                      float* __restrict__ out,
                                                      float* __restrict__ cls) {
    int wave = threadIdx.x >> 6;
    int lane = threadIdx.x & 63;
    int pair = blockIdx.x * 4 + wave;   // 1536
    int n = pair / PP;
    int p = pair % PP;
    int d = (p >> 5) + 1;
    int H = SS - 3 * d;
    float pnv = fmaxf(pn[p], EPS);
    float best = -3.4e38f;
    for (int h = lane; h < H; h += 64) {
        float dot = 0.f, x2 = 0.f;
#pragma unroll
        for (int j = 0; j < 4; j++) {
            int q = h * 4 + j;
            int k = q / H;
            int s = q - k * H + k * d;
            int r = n * SS + s;
            size_t off = (size_t)(4 * p + j) * NROWS + r;
            dot += Rt[off] + Rt[(size_t)NJ * NROWS + off];
            x2 += rn2[r];
        }
        float xn = fmaxf(sqrtf(x2), EPS);
        best = fmaxf(best, dot / (xn * pnv));
    }
#pragma unroll
    for (int off = 32; off; off >>= 1) best = fmaxf(best, __shfl_down(best, off));
    if (lane == 0) {
        float pdv = -best;
        out[n * PP + p] = pdv;
        atomicAdd(&cls[n * 2 + 0], pdv * fcw[p]);
        atomicAdd(&cls[n * 2 + 1], pdv * fcw[PP + p]);
    }
}

extern "C" void kernel_launch(void* const* d_in, const int* in_sizes, int n_in,
                              void* d_out, int out_size, void* d_ws, size_t ws_size,
                              hipStream_t stream) {
    const float* emb = (const float*)d_in[0];     // (16,512,1024) f32
    const float* proto = (const float*)d_in[2];   // (96,1024,4) f32 flat = (384,1024)
    const float* fcw = (const float*)d_in[3];     // (2,96)
    float* out = (float*)d_out;
    float* cls = out + NBATCH * PP;

    uint8_t* ws = (uint8_t*)d_ws;
    ushort* ebf = (ushort*)ws;                                   // 16 MB
    ushort* pbf = (ushort*)(ws + (size_t)NROWS * EE * 2);        // 0.75 MB
    float* rn2 = (float*)(ws + (size_t)NROWS * EE * 2 + (size_t)NJ * EE * 2);
    float* pn = rn2 + NROWS;
    float* Rt = pn + 128;  // 16B-aligned; 2 planes of NJ*NROWS f32

    conv_kernel<<<NROWS / 4 + PP, 256, 0, stream>>>(emb, proto, ebf, pbf, rn2, pn, cls);
    gemm_kernel<<<192 * NSPLIT, 256, 0, stream>>>(ebf, pbf, Rt);
    combine_kernel<<<NBATCH * PP / 4, 256, 0, stream>>>(Rt, rn2, pn, fcw, out, cls);
}

// Round 6
// 59.954 us; speedup vs baseline: 1.0519x; 1.0519x over previous
//
#include <hip/hip_runtime.h>
#include <stdint.h>

#define EE 1024
#define SS 512
#define NBATCH 16
#define PP 96
#define NROWS (NBATCH * SS)   // 8192
#define NJ (PP * 4)           // 384
#define EPS 1e-8f

typedef __attribute__((ext_vector_type(8))) short bf16x8;
typedef __attribute__((ext_vector_type(4))) float f32x4;

// round-to-nearest-even f32 -> bf16 bits
__device__ __forceinline__ ushort f2bf(float f) {
    uint32_t u = __float_as_uint(f);
    u += 0x7fffu + ((u >> 16) & 1u);
    return (ushort)(u >> 16);
}

__device__ __forceinline__ void gload16(const void* g, void* l) {
    __builtin_amdgcn_global_load_lds(
        (const __attribute__((address_space(1))) uint32_t*)g,
        (__attribute__((address_space(3))) uint32_t*)l, 16, 0, 0);
}

// ---- fused convert: emb (wave-per-row, 4xfloat4/lane) + proto; zeros cls ----
__global__ __launch_bounds__(256) void conv_kernel(const float* __restrict__ emb,
                                                   const float* __restrict__ proto,
                                                   ushort* __restrict__ ebf,
                                                   ushort* __restrict__ pbf,
                                                   float* __restrict__ rn2,
                                                   float* __restrict__ pn,
                                                   float* __restrict__ cls) {
    int b = blockIdx.x, t = threadIdx.x;
    if (b < NROWS / 4) {
        int r = b * 4 + (t >> 6);
        int l = t & 63;
        const float4* src = (const float4*)(emb + (size_t)r * EE);
        ushort4* dst = (ushort4*)(ebf + (size_t)r * EE);
        float s = 0.f;
#pragma unroll
        for (int i = 0; i < 4; i++) {
            float4 v = src[l + 64 * i];
            dst[l + 64 * i] = make_ushort4(f2bf(v.x), f2bf(v.y), f2bf(v.z), f2bf(v.w));
            s += v.x * v.x + v.y * v.y + v.z * v.z + v.w * v.w;
        }
#pragma unroll
        for (int off = 32; off; off >>= 1) s += __shfl_down(s, off);
        if (l == 0) rn2[r] = s;
    } else {
        int p = b - NROWS / 4;
        if (p == 0 && t < NBATCH * 2) cls[t] = 0.f;   // zero FC accumulators
        const float4* src = (const float4*)(proto + (size_t)p * 4096);
        ushort4* dst = (ushort4*)(pbf + (size_t)p * 4096);
        float s = 0.f;
#pragma unroll
        for (int i = 0; i < 4; i++) {
            float4 v = src[t + 256 * i];
            dst[t + 256 * i] = make_ushort4(f2bf(v.x), f2bf(v.y), f2bf(v.z), f2bf(v.w));
            s += v.x * v.x + v.y * v.y + v.z * v.z + v.w * v.w;
        }
#pragma unroll
        for (int off = 32; off; off >>= 1) s += __shfl_down(s, off);
        __shared__ float red[4];
        if ((t & 63) == 0) red[t >> 6] = s;
        __syncthreads();
        if (t == 0) pn[p] = sqrtf(red[0] + red[1] + red[2] + red[3]);
    }
}

// ---- bf16 MFMA GEMM: Rt[split][j][r], 128x128 tile, GBK=32, K-split 2, XCD swizzle ----
#define GBM 128
#define GBN 128
#define GBK 32
#define NSPLIT 2

__global__ __launch_bounds__(256) void gemm_kernel(const ushort* __restrict__ A,
                                                   const ushort* __restrict__ B,
                                                   float* __restrict__ Rt) {
    __shared__ ushort As[GBM * GBK];
    __shared__ ushort Bs[GBN * GBK];
    // XCD-aware swizzle: 384 blocks, 8 XCDs, 48 per XCD. A-tile sharers
    // (bids differing by multiples of 64) keep identical bid%8 -> same XCD.
    int bid = blockIdx.x;
    int swz = (bid & 7) * 48 + (bid >> 3);
    int split = swz / 192;
    int rem = swz - split * 192;
    int bm = rem & 63;
    int bn = rem >> 6;
    const int klen = EE / NSPLIT;   // 512
    int kb = split * klen;
    int r0 = bm * GBM, j0 = bn * GBN;
    int tid = threadIdx.x;
    int lane = tid & 63;

    // staging: thread t -> LDS linear byte t*16 (= row t/4, chunk t&3 of 32-elem row)
    // pre-swizzled global chunk: c ^ (row & 3)   (involution)
    int srow = tid >> 2;
    int schunk = (tid & 3) ^ (srow & 3);
    const ushort* ga = A + (size_t)(r0 + srow) * EE + kb + schunk * 8;
    const ushort* gb = B + (size_t)(j0 + srow) * EE + kb + schunk * 8;
    ushort* lA = As + tid * 8;
    ushort* lB = Bs + tid * 8;

    int w = tid >> 6;
    int wm = (w >> 1) * 64, wn = (w & 1) * 64;
    int kc = lane >> 4;          // k-chunk 0..3
    int fr = lane & 15;
    int fchunk = kc ^ (fr & 3);  // swizzled read chunk

    f32x4 acc[4][4] = {};

    for (int k0 = 0; k0 < klen; k0 += GBK) {
        __syncthreads();
        gload16(ga + k0, lA);
        gload16(ga + 64 * EE + k0, lA + 2048);
        gload16(gb + k0, lB);
        gload16(gb + 64 * EE + k0, lB + 2048);
        __syncthreads();
        bf16x8 af[4], bfr[4];
#pragma unroll
        for (int m = 0; m < 4; m++)
            af[m] = *(const bf16x8*)(As + (wm + m * 16 + fr) * GBK + fchunk * 8);
#pragma unroll
        for (int n = 0; n < 4; n++)
            bfr[n] = *(const bf16x8*)(Bs + (wn + n * 16 + fr) * GBK + fchunk * 8);
#pragma unroll
        for (int m = 0; m < 4; m++)
#pragma unroll
            for (int n = 0; n < 4; n++)
                acc[m][n] = __builtin_amdgcn_mfma_f32_16x16x32_bf16(af[m], bfr[n], acc[m][n], 0, 0, 0);
    }

    float* Rbase = Rt + (size_t)split * NJ * NROWS;
    int rloc = r0 + wm + (lane >> 4) * 4;
    int jloc = j0 + wn + fr;
#pragma unroll
    for (int m = 0; m < 4; m++)
#pragma unroll
        for (int n = 0; n < 4; n++)
            *(f32x4*)(Rbase + (size_t)(jloc + n * 16) * NROWS + rloc + m * 16) = acc[m][n];
}

// ---- combine v2: coalesced stage -> LDS scatter; min-pool of -cos; fused FC ----
// block = (n, group of 4 prototypes); wave w handles p = pg*4 + w.
#define CPAD 520   // row stride in floats; de-phases j-rows across bank groups

__global__ __launch_bounds__(256) void combine_kernel(const float* __restrict__ Rt,
                                                      const float* __restrict__ rn2,
                                                      const float* __restrict__ pn,
                                                      const float* __restrict__ fcw,
                                                      float* __restrict__ out,
                                                      float* __restrict__ cls) {
    __shared__ float sR[4][4][CPAD];   // [wave][j][col]
    __shared__ float sN2[512];
    int b = blockIdx.x;
    int n = b & 15;           // 16 batches
    int pg = b >> 4;          // 0..23
    int t = threadIdx.x;
    int w = t >> 6, l = t & 63;
    int p = pg * 4 + w;

    // stage rn2 row for this n (coalesced, whole block)
    sN2[t] = rn2[n * SS + t];
    sN2[t + 256] = rn2[n * SS + t + 256];

    // stage this wave's 4 Rt rows, both K-split planes summed (coalesced float4)
#pragma unroll
    for (int j = 0; j < 4; j++) {
        const float4* r0 = (const float4*)(Rt + (size_t)(4 * p + j) * NROWS + n * SS);
        const float4* r1 = (const float4*)(Rt + (size_t)(NJ + 4 * p + j) * NROWS + n * SS);
        float4 a0 = r0[l], a1 = r0[l + 64];
        float4 b0 = r1[l], b1 = r1[l + 64];
        *(float4*)&sR[w][j][4 * l] =
            make_float4(a0.x + b0.x, a0.y + b0.y, a0.z + b0.z, a0.w + b0.w);
        *(float4*)&sR[w][j][256 + 4 * l] =
            make_float4(a1.x + b1.x, a1.y + b1.y, a1.z + b1.z, a1.w + b1.w);
    }
    __syncthreads();

    int d = (p >> 5) + 1;
    int H = SS - 3 * d;
    int Hd = H - d;
    float pnv = fmaxf(pn[p], EPS);
    float best = -3.4e38f;
    for (int h = l; h < H; h += 64) {
        float dot = 0.f, x2 = 0.f;
#pragma unroll
        for (int j = 0; j < 4; j++) {
            int q = h * 4 + j;
            int k = (q >= H) + (q >= 2 * H) + (q >= 3 * H);
            int s = q - k * Hd;
            dot += sR[w][j][s];
            x2 += sN2[s];
        }
        float xn = fmaxf(sqrtf(x2), EPS);
        best = fmaxf(best, dot / (xn * pnv));
    }
#pragma unroll
    for (int off = 32; off; off >>= 1) best = fmaxf(best, __shfl_down(best, off));
    if (l == 0) {
        float pdv = -best;
        out[n * PP + p] = pdv;
        atomicAdd(&cls[n * 2 + 0], pdv * fcw[p]);
        atomicAdd(&cls[n * 2 + 1], pdv * fcw[PP + p]);
    }
}

extern "C" void kernel_launch(void* const* d_in, const int* in_sizes, int n_in,
                              void* d_out, int out_size, void* d_ws, size_t ws_size,
                              hipStream_t stream) {
    const float* emb = (const float*)d_in[0];     // (16,512,1024) f32
    const float* proto = (const float*)d_in[2];   // (96,1024,4) f32 flat = (384,1024)
    const float* fcw = (const float*)d_in[3];     // (2,96)
    float* out = (float*)d_out;
    float* cls = out + NBATCH * PP;

    uint8_t* ws = (uint8_t*)d_ws;
    ushort* ebf = (ushort*)ws;                                   // 16 MB
    ushort* pbf = (ushort*)(ws + (size_t)NROWS * EE * 2);        // 0.75 MB
    float* rn2 = (float*)(ws + (size_t)NROWS * EE * 2 + (size_t)NJ * EE * 2);
    float* pn = rn2 + NROWS;
    float* Rt = pn + 128;  // 16B-aligned; 2 planes of NJ*NROWS f32

    conv_kernel<<<NROWS / 4 + PP, 256, 0, stream>>>(emb, proto, ebf, pbf, rn2, pn, cls);
    gemm_kernel<<<192 * NSPLIT, 256, 0, stream>>>(ebf, pbf, Rt);
    combine_kernel<<<NBATCH * PP / 4, 256, 0, stream>>>(Rt, rn2, pn, fcw, out, cls);
}

// Round 7
// 59.268 us; speedup vs baseline: 1.0641x; 1.0116x over previous
//
#include <hip/hip_runtime.h>
#include <stdint.h>

#define EE 1024
#define SS 512
#define NBATCH 16
#define PP 96
#define NROWS (NBATCH * SS)   // 8192
#define NJ (PP * 4)           // 384
#define EPS 1e-8f

typedef __attribute__((ext_vector_type(8))) short bf16x8;
typedef __attribute__((ext_vector_type(4))) float f32x4;

// round-to-nearest-even f32 -> bf16 bits
__device__ __forceinline__ ushort f2bf(float f) {
    uint32_t u = __float_as_uint(f);
    u += 0x7fffu + ((u >> 16) & 1u);
    return (ushort)(u >> 16);
}

__device__ __forceinline__ void gload16(const void* g, void* l) {
    __builtin_amdgcn_global_load_lds(
        (const __attribute__((address_space(1))) uint32_t*)g,
        (__attribute__((address_space(3))) uint32_t*)l, 16, 0, 0);
}

// ---- fused convert: emb (wave-per-row, 4xfloat4/lane) + proto; zeros cls ----
__global__ __launch_bounds__(256) void conv_kernel(const float* __restrict__ emb,
                                                   const float* __restrict__ proto,
                                                   ushort* __restrict__ ebf,
                                                   ushort* __restrict__ pbf,
                                                   float* __restrict__ rn2,
                                                   float* __restrict__ pn,
                                                   float* __restrict__ cls) {
    int b = blockIdx.x, t = threadIdx.x;
    if (b < NROWS / 4) {
        int r = b * 4 + (t >> 6);
        int l = t & 63;
        const float4* src = (const float4*)(emb + (size_t)r * EE);
        ushort4* dst = (ushort4*)(ebf + (size_t)r * EE);
        float s = 0.f;
#pragma unroll
        for (int i = 0; i < 4; i++) {
            float4 v = src[l + 64 * i];
            dst[l + 64 * i] = make_ushort4(f2bf(v.x), f2bf(v.y), f2bf(v.z), f2bf(v.w));
            s += v.x * v.x + v.y * v.y + v.z * v.z + v.w * v.w;
        }
#pragma unroll
        for (int off = 32; off; off >>= 1) s += __shfl_down(s, off);
        if (l == 0) rn2[r] = s;
    } else {
        int p = b - NROWS / 4;
        if (p == 0 && t < NBATCH * 2) cls[t] = 0.f;   // zero FC accumulators
        const float4* src = (const float4*)(proto + (size_t)p * 4096);
        ushort4* dst = (ushort4*)(pbf + (size_t)p * 4096);
        float s = 0.f;
#pragma unroll
        for (int i = 0; i < 4; i++) {
            float4 v = src[t + 256 * i];
            dst[t + 256 * i] = make_ushort4(f2bf(v.x), f2bf(v.y), f2bf(v.z), f2bf(v.w));
            s += v.x * v.x + v.y * v.y + v.z * v.z + v.w * v.w;
        }
#pragma unroll
        for (int off = 32; off; off >>= 1) s += __shfl_down(s, off);
        __shared__ float red[4];
        if ((t & 63) == 0) red[t >> 6] = s;
        __syncthreads();
        if (t == 0) pn[p] = sqrtf(red[0] + red[1] + red[2] + red[3]);
    }
}

// ---- bf16 MFMA GEMM, 2-phase double-buffered pipeline, K-split 4 ----
#define GBM 128
#define GBN 128
#define GBK 32
#define NSPLIT 4
#define KLEN (EE / NSPLIT)   // 256
#define NT (KLEN / GBK)      // 8

__global__ __launch_bounds__(256, 3) void gemm_kernel(const ushort* __restrict__ A,
                                                      const ushort* __restrict__ B,
                                                      float* __restrict__ Rt) {
    __shared__ ushort As[2][GBM * GBK];   // 2 x 8 KB
    __shared__ ushort Bs[2][GBN * GBK];   // 2 x 8 KB
    int bid = blockIdx.x;                 // 768 blocks
    int split = bid / 192;
    int rem = bid - split * 192;
    int bm = rem & 63;
    int bn = rem >> 6;
    int kb = split * KLEN;
    int r0 = bm * GBM, j0 = bn * GBN;
    int tid = threadIdx.x;
    int lane = tid & 63;

    // staging: thread t -> LDS bytes t*16 (= row t/4, chunk t&3 of a 32-elem row)
    // pre-swizzled global chunk: c ^ (row & 3)  (involution)
    int srow = tid >> 2;
    int schunk = (tid & 3) ^ (srow & 3);
    const ushort* ga = A + (size_t)(r0 + srow) * EE + kb + schunk * 8;
    const ushort* gb = B + (size_t)(j0 + srow) * EE + kb + schunk * 8;

    int w = tid >> 6;
    int wm = (w >> 1) * 64, wn = (w & 1) * 64;
    int kc = lane >> 4;          // k-chunk 0..3
    int fr = lane & 15;
    int fchunk = kc ^ (fr & 3);  // swizzled read chunk

    f32x4 acc[4][4] = {};

    // prologue: stage tile 0 into buffer 0
    gload16(ga, &As[0][tid * 8]);
    gload16(ga + 64 * EE, &As[0][tid * 8 + 2048]);
    gload16(gb, &Bs[0][tid * 8]);
    gload16(gb + 64 * EE, &Bs[0][tid * 8 + 2048]);
    __syncthreads();

#pragma unroll
    for (int t = 0; t < NT; ++t) {
        int cur = t & 1;
        if (t + 1 < NT) {          // issue next-tile stage BEFORE compute
            int k0 = (t + 1) * GBK;
            int nb = cur ^ 1;
            gload16(ga + k0, &As[nb][tid * 8]);
            gload16(ga + 64 * EE + k0, &As[nb][tid * 8 + 2048]);
            gload16(gb + k0, &Bs[nb][tid * 8]);
            gload16(gb + 64 * EE + k0, &Bs[nb][tid * 8 + 2048]);
        }
        const ushort* as = As[cur];
        const ushort* bs = Bs[cur];
        bf16x8 af[4], bfr[4];
#pragma unroll
        for (int m = 0; m < 4; m++)
            af[m] = *(const bf16x8*)(as + (wm + m * 16 + fr) * GBK + fchunk * 8);
#pragma unroll
        for (int n = 0; n < 4; n++)
            bfr[n] = *(const bf16x8*)(bs + (wn + n * 16 + fr) * GBK + fchunk * 8);
#pragma unroll
        for (int m = 0; m < 4; m++)
#pragma unroll
            for (int n = 0; n < 4; n++)
                acc[m][n] = __builtin_amdgcn_mfma_f32_16x16x32_bf16(af[m], bfr[n], acc[m][n], 0, 0, 0);
        __syncthreads();   // drains vmcnt (next buf staged) + all reads of cur done
    }

    float* Rbase = Rt + (size_t)split * NJ * NROWS;
    int rloc = r0 + wm + (lane >> 4) * 4;
    int jloc = j0 + wn + fr;
#pragma unroll
    for (int m = 0; m < 4; m++)
#pragma unroll
        for (int n = 0; n < 4; n++)
            *(f32x4*)(Rbase + (size_t)(jloc + n * 16) * NROWS + rloc + m * 16) = acc[m][n];
}

// ---- combine: coalesced stage (sum 4 K-split planes) -> LDS gather; fused FC ----
#define CPAD 520

__global__ __launch_bounds__(256) void combine_kernel(const float* __restrict__ Rt,
                                                      const float* __restrict__ rn2,
                                                      const float* __restrict__ pn,
                                                      const float* __restrict__ fcw,
                                                      float* __restrict__ out,
                                                      float* __restrict__ cls) {
    __shared__ float sR[4][4][CPAD];   // [wave][j][col]
    __shared__ float sN2[512];
    int b = blockIdx.x;
    int n = b & 15;
    int pg = b >> 4;
    int t = threadIdx.x;
    int w = t >> 6, l = t & 63;
    int p = pg * 4 + w;

    sN2[t] = rn2[n * SS + t];
    sN2[t + 256] = rn2[n * SS + t + 256];

#pragma unroll
    for (int j = 0; j < 4; j++) {
        float4 s0 = make_float4(0.f, 0.f, 0.f, 0.f);
        float4 s1 = make_float4(0.f, 0.f, 0.f, 0.f);
#pragma unroll
        for (int pl = 0; pl < NSPLIT; pl++) {
            const float4* rp = (const float4*)(Rt + ((size_t)pl * NJ + 4 * p + j) * NROWS + n * SS);
            float4 a0 = rp[l], a1 = rp[l + 64];
            s0.x += a0.x; s0.y += a0.y; s0.z += a0.z; s0.w += a0.w;
            s1.x += a1.x; s1.y += a1.y; s1.z += a1.z; s1.w += a1.w;
        }
        *(float4*)&sR[w][j][4 * l] = s0;
        *(float4*)&sR[w][j][256 + 4 * l] = s1;
    }
    __syncthreads();

    int d = (p >> 5) + 1;
    int H = SS - 3 * d;
    int Hd = H - d;
    float pnv = fmaxf(pn[p], EPS);
    float best = -3.4e38f;
    for (int h = l; h < H; h += 64) {
        float dot = 0.f, x2 = 0.f;
#pragma unroll
        for (int j = 0; j < 4; j++) {
            int q = h * 4 + j;
            int k = (q >= H) + (q >= 2 * H) + (q >= 3 * H);
            int s = q - k * Hd;
            dot += sR[w][j][s];
            x2 += sN2[s];
        }
        float xn = fmaxf(sqrtf(x2), EPS);
        best = fmaxf(best, dot / (xn * pnv));
    }
#pragma unroll
    for (int off = 32; off; off >>= 1) best = fmaxf(best, __shfl_down(best, off));
    if (l == 0) {
        float pdv = -best;
        out[n * PP + p] = pdv;
        atomicAdd(&cls[n * 2 + 0], pdv * fcw[p]);
        atomicAdd(&cls[n * 2 + 1], pdv * fcw[PP + p]);
    }
}

extern "C" void kernel_launch(void* const* d_in, const int* in_sizes, int n_in,
                              void* d_out, int out_size, void* d_ws, size_t ws_size,
                              hipStream_t stream) {
    const float* emb = (const float*)d_in[0];     // (16,512,1024) f32
    const float* proto = (const float*)d_in[2];   // (96,1024,4) f32 flat = (384,1024)
    const float* fcw = (const float*)d_in[3];     // (2,96)
    float* out = (float*)d_out;
    float* cls = out + NBATCH * PP;

    uint8_t* ws = (uint8_t*)d_ws;
    ushort* ebf = (ushort*)ws;                                   // 16 MB
    ushort* pbf = (ushort*)(ws + (size_t)NROWS * EE * 2);        // 0.75 MB
    float* rn2 = (float*)(ws + (size_t)NROWS * EE * 2 + (size_t)NJ * EE * 2);
    float* pn = rn2 + NROWS;
    float* Rt = pn + 128;  // 16B-aligned; NSPLIT planes of NJ*NROWS f32

    conv_kernel<<<NROWS / 4 + PP, 256, 0, stream>>>(emb, proto, ebf, pbf, rn2, pn, cls);
    gemm_kernel<<<192 * NSPLIT, 256, 0, stream>>>(ebf, pbf, Rt);
    combine_kernel<<<NBATCH * PP / 4, 256, 0, stream>>>(Rt, rn2, pn, fcw, out, cls);
}